// Round 11
// baseline (502.958 us; speedup 1.0000x reference)
//
#include <hip/hip_runtime.h>

#define NN 100000
#define NE 1600000
#define NQ (NE / 4)                              // 400000
#define SCAN_B 1024
#define NBLK_SCAN ((NN + SCAN_B - 1) / SCAN_B)   // 98

__device__ __forceinline__ float wave_red(float v) {
#pragma unroll
    for (int off = 32; off > 0; off >>= 1) v += __shfl_down(v, off, 64);
    return v;
}

// ---------------- build phase (once per call) --------------------------------
__global__ __launch_bounds__(256) void build1_kernel(
    const int* __restrict__ ei, int* __restrict__ cnt, int* __restrict__ posArr)
{
    int e = blockIdx.x * 256 + threadIdx.x;
    if (e < NE) posArr[e] = atomicAdd(&cnt[ei[e]], 1);
}

__global__ __launch_bounds__(SCAN_B) void scan1_kernel(
    const int* __restrict__ cnt, int* __restrict__ bsum)
{
    int i = blockIdx.x * SCAN_B + threadIdx.x;
    int v = (i < NN) ? cnt[i] : 0;
#pragma unroll
    for (int off = 32; off > 0; off >>= 1) v += __shfl_down(v, off, 64);
    __shared__ int wsum[16];
    int wave = threadIdx.x >> 6, lane = threadIdx.x & 63;
    if (lane == 0) wsum[wave] = v;
    __syncthreads();
    if (threadIdx.x == 0) {
        int s = 0;
#pragma unroll
        for (int w = 0; w < 16; w++) s += wsum[w];
        bsum[blockIdx.x] = s;
    }
}

__global__ void scan2_kernel(const int* __restrict__ bsum, int* __restrict__ bexcl,
                             int* __restrict__ off)
{
    if (threadIdx.x == 0 && blockIdx.x == 0) {
        int s = 0;
        for (int b = 0; b < NBLK_SCAN; b++) { bexcl[b] = s; s += bsum[b]; }
        off[NN] = s;
    }
}

// off aliases cnt: each block reads its own cnt range, then overwrites with off.
__global__ __launch_bounds__(SCAN_B) void scan3_kernel(
    const int* cnt, const int* __restrict__ bexcl, int* off)
{
    __shared__ int buf[2][SCAN_B];
    int t = threadIdx.x;
    int i = blockIdx.x * SCAN_B + t;
    int v = (i < NN) ? cnt[i] : 0;
    buf[0][t] = v;
    __syncthreads();
    int src = 0;
    for (int d = 1; d < SCAN_B; d <<= 1) {
        int nv = buf[src][t] + ((t >= d) ? buf[src][t - d] : 0);
        buf[src ^ 1][t] = nv;
        src ^= 1;
        __syncthreads();
    }
    if (i < NN) off[i] = bexcl[blockIdx.x] + buf[src][t] - v;   // exclusive
}

// row-sorted records {row, col, ea0, ea1}: ONE 16B scatter per edge
__global__ __launch_bounds__(256) void fill2_kernel(
    const int* __restrict__ ei, const int* __restrict__ posArr,
    const int* __restrict__ off, const float* __restrict__ eattr,
    float4* __restrict__ rec)
{
    int e = blockIdx.x * 256 + threadIdx.x;
    if (e < NE) {
        int row = ei[e];
        int j = off[row] + posArr[e];
        float2 ea = reinterpret_cast<const float2*>(eattr)[e];
        float4 v;
        v.x = __int_as_float(row);
        v.y = __int_as_float(ei[NE + e]);
        v.z = ea.x; v.w = ea.y;
        rec[j] = v;
    }
}

// ---- P precompute for layer 0: Pr[i]=x[i]@W1[1:9], Pc[i]=x[i]@W1[9:17] ------
__global__ __launch_bounds__(256) void prep_kernel(
    const float* __restrict__ x, const float* __restrict__ W1,
    float* __restrict__ Pr, float* __restrict__ Pc)
{
    int i = blockIdx.x * 256 + threadIdx.x;
    if (i >= NN) return;
    const float4* xi = reinterpret_cast<const float4*>(x + (size_t)i * 8);
    float4 a0 = xi[0], a1 = xi[1];
    float xv[8] = {a0.x, a0.y, a0.z, a0.w, a1.x, a1.y, a1.z, a1.w};
    float pr[16], pc[16];
#pragma unroll
    for (int q = 0; q < 16; q++) { pr[q] = 0.f; pc[q] = 0.f; }
#pragma unroll
    for (int k = 0; k < 8; k++) {
        float v = xv[k];
#pragma unroll
        for (int q = 0; q < 16; q++) {
            pr[q] += v * W1[(1 + k) * 16 + q];
            pc[q] += v * W1[(9 + k) * 16 + q];
        }
    }
    float4* po = reinterpret_cast<float4*>(Pr + (size_t)i * 16);
#pragma unroll
    for (int t = 0; t < 4; t++)
        po[t] = make_float4(pr[4 * t], pr[4 * t + 1], pr[4 * t + 2], pr[4 * t + 3]);
    float4* qo = reinterpret_cast<float4*>(Pc + (size_t)i * 16);
#pragma unroll
    for (int t = 0; t < 4; t++)
        qo[t] = make_float4(pc[4 * t], pc[4 * t + 1], pc[4 * t + 2], pc[4 * t + 3]);
}

// ---------------- edge block: refactored MLP, 4 edges/thread -----------------
// h = (B1 + g*W1[0]) + Pr[row] + Pc[col] + ea0*W1[17] + ea1*W1[18]
// EIN_FROM_REC: edge attrs come from rec.zw (free, same 16B load as row/col).
// WRITE_REC:    output written as full 16B {row,col,o0,o1} back into rec
//               (dense coalesced rewrite — NOT r9's strided 8B partial store).
template <bool EIN_FROM_REC, bool WRITE_REC, bool NEED_SUM>
__global__ __launch_bounds__(256, 4) void edge_kernel(
    float4* __restrict__ rec,
    const float* __restrict__ Pr, const float* __restrict__ Pc,
    const float* __restrict__ ein, const float* __restrict__ gptr,
    const float* __restrict__ W1, const float* __restrict__ B1,
    const float* __restrict__ W2, const float* __restrict__ B2,
    float* __restrict__ eout, float* __restrict__ esum)
{
    int j = blockIdx.x * 256 + threadIdx.x;
    float t0 = 0.f, t1 = 0.f;

    if (j < NQ) {
        float gval = gptr[0];
        float gterm[16];
#pragma unroll
        for (int q = 0; q < 16; q++) gterm[q] = B1[q] + gval * W1[q];

#pragma unroll
        for (int e = 0; e < 4; e++) {
            int jj = j + e * NQ;
            float4 r = rec[jj];
            int row = __float_as_int(r.x);
            int col = __float_as_int(r.y);
            float ea0, ea1;
            if (EIN_FROM_REC) { ea0 = r.z; ea1 = r.w; }
            else {
                float2 ea = reinterpret_cast<const float2*>(ein)[jj];
                ea0 = ea.x; ea1 = ea.y;
            }
            const float4* pr = reinterpret_cast<const float4*>(Pr + (size_t)row * 16);
            const float4* pc = reinterpret_cast<const float4*>(Pc + (size_t)col * 16);
            float4 r0 = pr[0], r1 = pr[1], r2 = pr[2], r3 = pr[3];
            float4 c0 = pc[0], c1 = pc[1], c2 = pc[2], c3 = pc[3];
            float h[16];
            h[0]  = gterm[0]  + r0.x + c0.x;
            h[1]  = gterm[1]  + r0.y + c0.y;
            h[2]  = gterm[2]  + r0.z + c0.z;
            h[3]  = gterm[3]  + r0.w + c0.w;
            h[4]  = gterm[4]  + r1.x + c1.x;
            h[5]  = gterm[5]  + r1.y + c1.y;
            h[6]  = gterm[6]  + r1.z + c1.z;
            h[7]  = gterm[7]  + r1.w + c1.w;
            h[8]  = gterm[8]  + r2.x + c2.x;
            h[9]  = gterm[9]  + r2.y + c2.y;
            h[10] = gterm[10] + r2.z + c2.z;
            h[11] = gterm[11] + r2.w + c2.w;
            h[12] = gterm[12] + r3.x + c3.x;
            h[13] = gterm[13] + r3.y + c3.y;
            h[14] = gterm[14] + r3.z + c3.z;
            h[15] = gterm[15] + r3.w + c3.w;
#pragma unroll
            for (int q = 0; q < 16; q++) {
                h[q] += ea0 * W1[17 * 16 + q];
                h[q] += ea1 * W1[18 * 16 + q];
            }
            float s0 = B2[0], s1 = B2[1];
#pragma unroll
            for (int q = 0; q < 16; q++) {
                float rr = fmaxf(h[q], 0.f);
                s0 += rr * W2[2 * q];
                s1 += rr * W2[2 * q + 1];
            }
            if (WRITE_REC) {
                float4 w;
                w.x = r.x; w.y = r.y; w.z = s0; w.w = s1;
                rec[jj] = w;
            } else {
                reinterpret_cast<float2*>(eout)[jj] = make_float2(s0, s1);
            }
            t0 += s0; t1 += s1;
        }
    }

    if (NEED_SUM) {
        float r0 = wave_red(t0);
        float r1 = wave_red(t1);
        __shared__ float red[4][2];
        int wave = threadIdx.x >> 6, lane = threadIdx.x & 63;
        if (lane == 0) { red[wave][0] = r0; red[wave][1] = r1; }
        __syncthreads();
        if (threadIdx.x == 0) {
            atomicAdd(&esum[0], red[0][0] + red[1][0] + red[2][0] + red[3][0]);
            atomicAdd(&esum[1], red[0][1] + red[1][1] + red[2][1] + red[3][1]);
        }
    }
}

// -------- node block: aggregate + MLP(11->16->8), fused next-layer P ---------
// EOUT_FROM_REC: edge embeddings read from rec.zw instead of a float2 buffer.
template <bool EOUT_FROM_REC, bool NEED_SUM, bool HAS_NEXT>
__global__ __launch_bounds__(256) void node_kernel(
    const float* __restrict__ x, const float* __restrict__ eout,
    const float4* __restrict__ rec,
    const int* __restrict__ off, const float* __restrict__ gptr,
    const float* __restrict__ W1, const float* __restrict__ B1,
    const float* __restrict__ W2, const float* __restrict__ B2,
    const float* __restrict__ nextW1,
    float* __restrict__ Pr, float* __restrict__ Pc,
    float* __restrict__ xout, float* __restrict__ nsum)
{
    int i = blockIdx.x * 256 + threadIdx.x;
    float out[8];
#pragma unroll
    for (int m = 0; m < 8; m++) out[m] = 0.f;

    if (i < NN) {
        float in[11];
        in[0] = gptr[0];
        const float4* xi = reinterpret_cast<const float4*>(x + (size_t)i * 8);
        float4 a0 = xi[0], a1 = xi[1];
        in[1] = a0.x; in[2] = a0.y; in[3] = a0.z; in[4] = a0.w;
        in[5] = a1.x; in[6] = a1.y; in[7] = a1.z; in[8] = a1.w;

        int b0 = off[i], b1 = off[i + 1];
        float s0 = 0.f, s1 = 0.f;
        if (EOUT_FROM_REC) {
            for (int j = b0; j < b1; j++) {
                float4 v = rec[j];
                s0 += v.z; s1 += v.w;
            }
        } else {
            const float2* e2 = reinterpret_cast<const float2*>(eout);
            const float4* e4 = reinterpret_cast<const float4*>(eout);
            int j = b0;
            if ((j & 1) && j < b1) { float2 v = e2[j]; s0 += v.x; s1 += v.y; j++; }
            for (; j + 2 <= b1; j += 2) {
                float4 v = e4[j >> 1];
                s0 += v.x + v.z; s1 += v.y + v.w;
            }
            if (j < b1) { float2 v = e2[j]; s0 += v.x; s1 += v.y; }
        }
        in[9] = s0; in[10] = s1;

        float h[16];
#pragma unroll
        for (int q = 0; q < 16; q++) h[q] = B1[q];
#pragma unroll
        for (int k = 0; k < 11; k++) {
            float v = in[k];
#pragma unroll
            for (int q = 0; q < 16; q++) h[q] += v * W1[k * 16 + q];
        }
#pragma unroll
        for (int m = 0; m < 8; m++) out[m] = B2[m];
#pragma unroll
        for (int q = 0; q < 16; q++) {
            float hq = fmaxf(h[q], 0.f);
#pragma unroll
            for (int m = 0; m < 8; m++) out[m] += hq * W2[q * 8 + m];
        }
        float4* xo = reinterpret_cast<float4*>(xout + (size_t)i * 8);
        xo[0] = make_float4(out[0], out[1], out[2], out[3]);
        xo[1] = make_float4(out[4], out[5], out[6], out[7]);

        if (HAS_NEXT) {
            float pr[16], pc[16];
#pragma unroll
            for (int q = 0; q < 16; q++) { pr[q] = 0.f; pc[q] = 0.f; }
#pragma unroll
            for (int k = 0; k < 8; k++) {
                float v = out[k];
#pragma unroll
                for (int q = 0; q < 16; q++) {
                    pr[q] += v * nextW1[(1 + k) * 16 + q];
                    pc[q] += v * nextW1[(9 + k) * 16 + q];
                }
            }
            float4* po = reinterpret_cast<float4*>(Pr + (size_t)i * 16);
#pragma unroll
            for (int t = 0; t < 4; t++)
                po[t] = make_float4(pr[4*t], pr[4*t+1], pr[4*t+2], pr[4*t+3]);
            float4* qo = reinterpret_cast<float4*>(Pc + (size_t)i * 16);
#pragma unroll
            for (int t = 0; t < 4; t++)
                qo[t] = make_float4(pc[4*t], pc[4*t+1], pc[4*t+2], pc[4*t+3]);
        }
    }
    if (NEED_SUM) {
        float r[8];
#pragma unroll
        for (int m = 0; m < 8; m++) r[m] = wave_red(out[m]);
        __shared__ float red[4][8];
        int wave = threadIdx.x >> 6, lane = threadIdx.x & 63;
        if (lane == 0) {
#pragma unroll
            for (int m = 0; m < 8; m++) red[wave][m] = r[m];
        }
        __syncthreads();
        if (threadIdx.x == 0) {
#pragma unroll
            for (int m = 0; m < 8; m++) {
                float s = red[0][m] + red[1][m] + red[2][m] + red[3][m];
                atomicAdd(&nsum[m], s);
            }
        }
    }
}

// ---------------- global block: MLP(11->16->1), single thread ----------------
__global__ void glob_kernel(const float* __restrict__ esum, const float* __restrict__ nsum,
                            const float* __restrict__ gold,
                            const float* __restrict__ W1, const float* __restrict__ B1,
                            const float* __restrict__ W2, const float* __restrict__ B2,
                            float* __restrict__ gnew)
{
    if (threadIdx.x == 0 && blockIdx.x == 0) {
        float in[11];
#pragma unroll
        for (int j = 0; j < 8; j++) in[j] = nsum[j] * (1.0f / NN);
        in[8] = esum[0] * (1.0f / NE);
        in[9] = esum[1] * (1.0f / NE);
        in[10] = gold[0];
        float acc = B2[0];
#pragma unroll
        for (int j = 0; j < 16; j++) {
            float h = B1[j];
#pragma unroll
            for (int k = 0; k < 11; k++) h += in[k] * W1[k * 16 + j];
            acc += fmaxf(h, 0.f) * W2[j];
        }
        gnew[0] = acc;
    }
}

extern "C" void kernel_launch(void* const* d_in, const int* in_sizes, int n_in,
                              void* d_out, int out_size, void* d_ws, size_t ws_size,
                              hipStream_t stream) {
    const float* x     = (const float*)d_in[0];
    const int*   ei    = (const int*)d_in[1];
    const float* eattr = (const float*)d_in[2];
    const float* g     = (const float*)d_in[3];
    const float* eW1 = (const float*)d_in[4];
    const float* eB1 = (const float*)d_in[5];
    const float* eW2 = (const float*)d_in[6];
    const float* eB2 = (const float*)d_in[7];
    const float* nW1 = (const float*)d_in[8];
    const float* nB1 = (const float*)d_in[9];
    const float* nW2 = (const float*)d_in[10];
    const float* nB2 = (const float*)d_in[11];
    const float* gW1 = (const float*)d_in[12];
    const float* gB1 = (const float*)d_in[13];
    const float* gW2 = (const float*)d_in[14];
    const float* gB2 = (const float*)d_in[15];
    float* out = (float*)d_out;

    char* ws = (char*)d_ws;
    float*  xb0    = (float*)(ws);                 // 3,200,000
    int*    off    = (int*)  (ws + 3200000);       // 400,004 (aliases cnt)
    int*    cnt    = off;
    int*    bsum   = (int*)  (ws + 3600064);       // 392
    int*    bexcl  = (int*)  (ws + 3600576);       // 392
    float*  esum   = (float*)(ws + 3601024);       // 2
    float*  nsum   = (float*)(ws + 3601056);       // 8
    float*  g1     = (float*)(ws + 3601088);
    float*  g2     = g1 + 1;
    float*  eb0    = (float*)(ws + 3601152);       // 12,800,000
    float4* rec    = (float4*)(ws + 16401152);     // 25,600,000
    float*  Pr     = (float*)(ws + 42001152);      // 6,400,000 (aliases posArr)
    int*    posArr = (int*)  Pr;
    float*  Pc     = (float*)(ws + 48401152);      // 6,400,000 -> ends 54,801,152
    float*  xb1    = out;                          // d_out doubles as x buffer

    dim3 blk(256);
    dim3 egrid(NE / 256);                          // 6250 (build/fill)
    dim3 e4grid((NQ + 255) / 256);                 // 1563 (edge MLP, 4 edges/thread)
    dim3 ngrid((NN + 255) / 256);                  // 391

    // ---- build row-sorted packed records (once per call) ----
    hipMemsetAsync(cnt, 0, 400000, stream);
    hipMemsetAsync(esum, 0, 64, stream);
    build1_kernel<<<egrid, blk, 0, stream>>>(ei, cnt, posArr);
    scan1_kernel<<<NBLK_SCAN, SCAN_B, 0, stream>>>(cnt, bsum);
    scan2_kernel<<<1, 64, 0, stream>>>(bsum, bexcl, off);
    scan3_kernel<<<NBLK_SCAN, SCAN_B, 0, stream>>>(cnt, bexcl, off);
    fill2_kernel<<<egrid, blk, 0, stream>>>(ei, posArr, off, eattr, rec);
    prep_kernel<<<ngrid, blk, 0, stream>>>(x, eW1, Pr, Pc);   // posArr dead now

    // ---- layer 0: ein = rec.zw -> eout eb0; node fuses P for L1 ----
    edge_kernel<true, false, true><<<e4grid, blk, 0, stream>>>(rec, Pr, Pc,
        nullptr, g, eW1, eB1, eW2, eB2, eb0, esum);
    node_kernel<false, true, true><<<ngrid, blk, 0, stream>>>(x, eb0, rec, off, g,
        nW1, nB1, nW2, nB2, eW1 + 304, Pr, Pc, xb0, nsum);
    glob_kernel<<<1, 64, 0, stream>>>(esum, nsum, g, gW1, gB1, gW2, gB2, g1);

    // ---- layer 1: ein = eb0 -> eout rec.zw (full 16B rewrite); node reads rec
    hipMemsetAsync(esum, 0, 64, stream);
    edge_kernel<false, true, true><<<e4grid, blk, 0, stream>>>(rec, Pr, Pc,
        eb0, g1, eW1 + 304, eB1 + 16, eW2 + 32, eB2 + 2, nullptr, esum);
    node_kernel<true, true, true><<<ngrid, blk, 0, stream>>>(xb0, nullptr, rec, off, g1,
        nW1 + 176, nB1 + 16, nW2 + 128, nB2 + 8, eW1 + 608, Pr, Pc, xb1, nsum);
    glob_kernel<<<1, 64, 0, stream>>>(esum, nsum, g1, gW1 + 176, gB1 + 16, gW2 + 16, gB2 + 1, g2);

    // ---- layer 2: ein = rec.zw -> eout eb0; node output -> d_out ----
    edge_kernel<true, false, false><<<e4grid, blk, 0, stream>>>(rec, Pr, Pc,
        nullptr, g2, eW1 + 608, eB1 + 32, eW2 + 64, eB2 + 4, eb0, esum);
    node_kernel<false, false, false><<<ngrid, blk, 0, stream>>>(xb1, eb0, rec, off, g2,
        nW1 + 352, nB1 + 32, nW2 + 256, nB2 + 16, nullptr, nullptr, nullptr, out, nsum);
}

// Round 12
// 449.117 us; speedup vs baseline: 1.1199x; 1.1199x over previous
//
#include <hip/hip_runtime.h>

#define NN 100000
#define NE 1600000
#define NO8 (NE / 8)                             // 200000 edges per eighth
#define SCAN_B 1024
#define NBLK_SCAN ((NN + SCAN_B - 1) / SCAN_B)   // 98

__device__ __forceinline__ float wave_red(float v) {
#pragma unroll
    for (int off = 32; off > 0; off >>= 1) v += __shfl_down(v, off, 64);
    return v;
}

// ---------------- build phase (once per call) --------------------------------
__global__ __launch_bounds__(256) void build1_kernel(
    const int* __restrict__ ei, int* __restrict__ cnt, int* __restrict__ posArr)
{
    int e = blockIdx.x * 256 + threadIdx.x;
    if (e < NE) posArr[e] = atomicAdd(&cnt[ei[e]], 1);
}

__global__ __launch_bounds__(SCAN_B) void scan1_kernel(
    const int* __restrict__ cnt, int* __restrict__ bsum)
{
    int i = blockIdx.x * SCAN_B + threadIdx.x;
    int v = (i < NN) ? cnt[i] : 0;
#pragma unroll
    for (int off = 32; off > 0; off >>= 1) v += __shfl_down(v, off, 64);
    __shared__ int wsum[16];
    int wave = threadIdx.x >> 6, lane = threadIdx.x & 63;
    if (lane == 0) wsum[wave] = v;
    __syncthreads();
    if (threadIdx.x == 0) {
        int s = 0;
#pragma unroll
        for (int w = 0; w < 16; w++) s += wsum[w];
        bsum[blockIdx.x] = s;
    }
}

// scan3 with scan2 folded in: each block derives its own prefix from bsum.
// off aliases cnt (block reads its cnt range before overwriting with off).
__global__ __launch_bounds__(SCAN_B) void scan3_kernel(
    const int* cnt, const int* __restrict__ bsum, int* off)
{
    __shared__ int sarr[NBLK_SCAN];
    __shared__ int sbase;
    int t = threadIdx.x;
    if (t < NBLK_SCAN) sarr[t] = bsum[t];
    __syncthreads();
    if (t == 0) {
        int s = 0;
        for (int b = 0; b < (int)blockIdx.x; b++) s += sarr[b];
        sbase = s;
    }

    __shared__ int buf[2][SCAN_B];
    int i = blockIdx.x * SCAN_B + t;
    int v = (i < NN) ? cnt[i] : 0;
    buf[0][t] = v;
    __syncthreads();
    int src = 0;
    for (int d = 1; d < SCAN_B; d <<= 1) {
        int nv = buf[src][t] + ((t >= d) ? buf[src][t - d] : 0);
        buf[src ^ 1][t] = nv;
        src ^= 1;
        __syncthreads();
    }
    if (i < NN) off[i] = sbase + buf[src][t] - v;   // exclusive
    if (blockIdx.x == NBLK_SCAN - 1 && t == SCAN_B - 1)
        off[NN] = sbase + buf[src][t];              // inclusive total = NE
}

// row-sorted records {row, col, ea0, ea1}: ONE 16B scatter per edge
__global__ __launch_bounds__(256) void fill2_kernel(
    const int* __restrict__ ei, const int* __restrict__ posArr,
    const int* __restrict__ off, const float* __restrict__ eattr,
    float4* __restrict__ rec)
{
    int e = blockIdx.x * 256 + threadIdx.x;
    if (e < NE) {
        int row = ei[e];
        int j = off[row] + posArr[e];
        float2 ea = reinterpret_cast<const float2*>(eattr)[e];
        float4 v;
        v.x = __int_as_float(row);
        v.y = __int_as_float(ei[NE + e]);
        v.z = ea.x; v.w = ea.y;
        rec[j] = v;
    }
}

// ---- P precompute for layer 0: Pr[i]=x[i]@W1[1:9], Pc[i]=x[i]@W1[9:17] ------
__global__ __launch_bounds__(256) void prep_kernel(
    const float* __restrict__ x, const float* __restrict__ W1,
    float* __restrict__ Pr, float* __restrict__ Pc)
{
    int i = blockIdx.x * 256 + threadIdx.x;
    if (i >= NN) return;
    const float4* xi = reinterpret_cast<const float4*>(x + (size_t)i * 8);
    float4 a0 = xi[0], a1 = xi[1];
    float xv[8] = {a0.x, a0.y, a0.z, a0.w, a1.x, a1.y, a1.z, a1.w};
    float pr[16], pc[16];
#pragma unroll
    for (int q = 0; q < 16; q++) { pr[q] = 0.f; pc[q] = 0.f; }
#pragma unroll
    for (int k = 0; k < 8; k++) {
        float v = xv[k];
#pragma unroll
        for (int q = 0; q < 16; q++) {
            pr[q] += v * W1[(1 + k) * 16 + q];
            pc[q] += v * W1[(9 + k) * 16 + q];
        }
    }
    float4* po = reinterpret_cast<float4*>(Pr + (size_t)i * 16);
#pragma unroll
    for (int t = 0; t < 4; t++)
        po[t] = make_float4(pr[4 * t], pr[4 * t + 1], pr[4 * t + 2], pr[4 * t + 3]);
    float4* qo = reinterpret_cast<float4*>(Pc + (size_t)i * 16);
#pragma unroll
    for (int t = 0; t < 4; t++)
        qo[t] = make_float4(pc[4 * t], pc[4 * t + 1], pc[4 * t + 2], pc[4 * t + 3]);
}

// ---------------- edge block: refactored MLP, 8 edges/thread -----------------
// h = (B1 + g*W1[0]) + Pr[row] + Pc[col] + ea0*W1[17] + ea1*W1[18]
template <bool EIN_FROM_REC, bool WRITE_REC, bool NEED_SUM>
__global__ __launch_bounds__(256, 4) void edge_kernel(
    float4* __restrict__ rec,
    const float* __restrict__ Pr, const float* __restrict__ Pc,
    const float* __restrict__ ein, const float* __restrict__ gptr,
    const float* __restrict__ W1, const float* __restrict__ B1,
    const float* __restrict__ W2, const float* __restrict__ B2,
    float* __restrict__ eout, float* __restrict__ esum)
{
    int j = blockIdx.x * 256 + threadIdx.x;
    float t0 = 0.f, t1 = 0.f;

    if (j < NO8) {
        float gval = gptr[0];
        float gterm[16];
#pragma unroll
        for (int q = 0; q < 16; q++) gterm[q] = B1[q] + gval * W1[q];

#pragma unroll
        for (int e = 0; e < 8; e++) {
            int jj = j + e * NO8;
            float4 r = rec[jj];
            int row = __float_as_int(r.x);
            int col = __float_as_int(r.y);
            float ea0, ea1;
            if (EIN_FROM_REC) { ea0 = r.z; ea1 = r.w; }
            else {
                float2 ea = reinterpret_cast<const float2*>(ein)[jj];
                ea0 = ea.x; ea1 = ea.y;
            }
            const float4* pr = reinterpret_cast<const float4*>(Pr + (size_t)row * 16);
            const float4* pc = reinterpret_cast<const float4*>(Pc + (size_t)col * 16);
            float4 r0 = pr[0], r1 = pr[1], r2 = pr[2], r3 = pr[3];
            float4 c0 = pc[0], c1 = pc[1], c2 = pc[2], c3 = pc[3];
            float h[16];
            h[0]  = gterm[0]  + r0.x + c0.x;
            h[1]  = gterm[1]  + r0.y + c0.y;
            h[2]  = gterm[2]  + r0.z + c0.z;
            h[3]  = gterm[3]  + r0.w + c0.w;
            h[4]  = gterm[4]  + r1.x + c1.x;
            h[5]  = gterm[5]  + r1.y + c1.y;
            h[6]  = gterm[6]  + r1.z + c1.z;
            h[7]  = gterm[7]  + r1.w + c1.w;
            h[8]  = gterm[8]  + r2.x + c2.x;
            h[9]  = gterm[9]  + r2.y + c2.y;
            h[10] = gterm[10] + r2.z + c2.z;
            h[11] = gterm[11] + r2.w + c2.w;
            h[12] = gterm[12] + r3.x + c3.x;
            h[13] = gterm[13] + r3.y + c3.y;
            h[14] = gterm[14] + r3.z + c3.z;
            h[15] = gterm[15] + r3.w + c3.w;
#pragma unroll
            for (int q = 0; q < 16; q++) {
                h[q] += ea0 * W1[17 * 16 + q];
                h[q] += ea1 * W1[18 * 16 + q];
            }
            float s0 = B2[0], s1 = B2[1];
#pragma unroll
            for (int q = 0; q < 16; q++) {
                float rr = fmaxf(h[q], 0.f);
                s0 += rr * W2[2 * q];
                s1 += rr * W2[2 * q + 1];
            }
            if (WRITE_REC) {
                float4 w;
                w.x = r.x; w.y = r.y; w.z = s0; w.w = s1;
                rec[jj] = w;
            } else {
                reinterpret_cast<float2*>(eout)[jj] = make_float2(s0, s1);
            }
            t0 += s0; t1 += s1;
        }
    }

    if (NEED_SUM) {
        float r0 = wave_red(t0);
        float r1 = wave_red(t1);
        __shared__ float red[4][2];
        int wave = threadIdx.x >> 6, lane = threadIdx.x & 63;
        if (lane == 0) { red[wave][0] = r0; red[wave][1] = r1; }
        __syncthreads();
        if (threadIdx.x == 0) {
            atomicAdd(&esum[0], red[0][0] + red[1][0] + red[2][0] + red[3][0]);
            atomicAdd(&esum[1], red[0][1] + red[1][1] + red[2][1] + red[3][1]);
        }
    }
}

// -------- node block: aggregate + MLP(11->16->8), fused next-layer P ---------
template <bool EOUT_FROM_REC, bool NEED_SUM, bool HAS_NEXT>
__global__ __launch_bounds__(256) void node_kernel(
    const float* __restrict__ x, const float* __restrict__ eout,
    const float4* __restrict__ rec,
    const int* __restrict__ off, const float* __restrict__ gptr,
    const float* __restrict__ W1, const float* __restrict__ B1,
    const float* __restrict__ W2, const float* __restrict__ B2,
    const float* __restrict__ nextW1,
    float* __restrict__ Pr, float* __restrict__ Pc,
    float* __restrict__ xout, float* __restrict__ nsum)
{
    int i = blockIdx.x * 256 + threadIdx.x;
    float out[8];
#pragma unroll
    for (int m = 0; m < 8; m++) out[m] = 0.f;

    if (i < NN) {
        float in[11];
        in[0] = gptr[0];
        const float4* xi = reinterpret_cast<const float4*>(x + (size_t)i * 8);
        float4 a0 = xi[0], a1 = xi[1];
        in[1] = a0.x; in[2] = a0.y; in[3] = a0.z; in[4] = a0.w;
        in[5] = a1.x; in[6] = a1.y; in[7] = a1.z; in[8] = a1.w;

        int b0 = off[i], b1 = off[i + 1];
        float s0 = 0.f, s1 = 0.f;
        if (EOUT_FROM_REC) {
            for (int j = b0; j < b1; j++) {
                float4 v = rec[j];
                s0 += v.z; s1 += v.w;
            }
        } else {
            const float2* e2 = reinterpret_cast<const float2*>(eout);
            const float4* e4 = reinterpret_cast<const float4*>(eout);
            int j = b0;
            if ((j & 1) && j < b1) { float2 v = e2[j]; s0 += v.x; s1 += v.y; j++; }
            for (; j + 2 <= b1; j += 2) {
                float4 v = e4[j >> 1];
                s0 += v.x + v.z; s1 += v.y + v.w;
            }
            if (j < b1) { float2 v = e2[j]; s0 += v.x; s1 += v.y; }
        }
        in[9] = s0; in[10] = s1;

        float h[16];
#pragma unroll
        for (int q = 0; q < 16; q++) h[q] = B1[q];
#pragma unroll
        for (int k = 0; k < 11; k++) {
            float v = in[k];
#pragma unroll
            for (int q = 0; q < 16; q++) h[q] += v * W1[k * 16 + q];
        }
#pragma unroll
        for (int m = 0; m < 8; m++) out[m] = B2[m];
#pragma unroll
        for (int q = 0; q < 16; q++) {
            float hq = fmaxf(h[q], 0.f);
#pragma unroll
            for (int m = 0; m < 8; m++) out[m] += hq * W2[q * 8 + m];
        }
        float4* xo = reinterpret_cast<float4*>(xout + (size_t)i * 8);
        xo[0] = make_float4(out[0], out[1], out[2], out[3]);
        xo[1] = make_float4(out[4], out[5], out[6], out[7]);

        if (HAS_NEXT) {
            float pr[16], pc[16];
#pragma unroll
            for (int q = 0; q < 16; q++) { pr[q] = 0.f; pc[q] = 0.f; }
#pragma unroll
            for (int k = 0; k < 8; k++) {
                float v = out[k];
#pragma unroll
                for (int q = 0; q < 16; q++) {
                    pr[q] += v * nextW1[(1 + k) * 16 + q];
                    pc[q] += v * nextW1[(9 + k) * 16 + q];
                }
            }
            float4* po = reinterpret_cast<float4*>(Pr + (size_t)i * 16);
#pragma unroll
            for (int t = 0; t < 4; t++)
                po[t] = make_float4(pr[4*t], pr[4*t+1], pr[4*t+2], pr[4*t+3]);
            float4* qo = reinterpret_cast<float4*>(Pc + (size_t)i * 16);
#pragma unroll
            for (int t = 0; t < 4; t++)
                qo[t] = make_float4(pc[4*t], pc[4*t+1], pc[4*t+2], pc[4*t+3]);
        }
    }
    if (NEED_SUM) {
        float r[8];
#pragma unroll
        for (int m = 0; m < 8; m++) r[m] = wave_red(out[m]);
        __shared__ float red[4][8];
        int wave = threadIdx.x >> 6, lane = threadIdx.x & 63;
        if (lane == 0) {
#pragma unroll
            for (int m = 0; m < 8; m++) red[wave][m] = r[m];
        }
        __syncthreads();
        if (threadIdx.x == 0) {
#pragma unroll
            for (int m = 0; m < 8; m++) {
                float s = red[0][m] + red[1][m] + red[2][m] + red[3][m];
                atomicAdd(&nsum[m], s);
            }
        }
    }
}

// ---------------- global block: MLP(11->16->1), single thread ----------------
__global__ void glob_kernel(const float* __restrict__ esum, const float* __restrict__ nsum,
                            const float* __restrict__ gold,
                            const float* __restrict__ W1, const float* __restrict__ B1,
                            const float* __restrict__ W2, const float* __restrict__ B2,
                            float* __restrict__ gnew)
{
    if (threadIdx.x == 0 && blockIdx.x == 0) {
        float in[11];
#pragma unroll
        for (int j = 0; j < 8; j++) in[j] = nsum[j] * (1.0f / NN);
        in[8] = esum[0] * (1.0f / NE);
        in[9] = esum[1] * (1.0f / NE);
        in[10] = gold[0];
        float acc = B2[0];
#pragma unroll
        for (int j = 0; j < 16; j++) {
            float h = B1[j];
#pragma unroll
            for (int k = 0; k < 11; k++) h += in[k] * W1[k * 16 + j];
            acc += fmaxf(h, 0.f) * W2[j];
        }
        gnew[0] = acc;
    }
}

extern "C" void kernel_launch(void* const* d_in, const int* in_sizes, int n_in,
                              void* d_out, int out_size, void* d_ws, size_t ws_size,
                              hipStream_t stream) {
    const float* x     = (const float*)d_in[0];
    const int*   ei    = (const int*)d_in[1];
    const float* eattr = (const float*)d_in[2];
    const float* g     = (const float*)d_in[3];
    const float* eW1 = (const float*)d_in[4];
    const float* eB1 = (const float*)d_in[5];
    const float* eW2 = (const float*)d_in[6];
    const float* eB2 = (const float*)d_in[7];
    const float* nW1 = (const float*)d_in[8];
    const float* nB1 = (const float*)d_in[9];
    const float* nW2 = (const float*)d_in[10];
    const float* nB2 = (const float*)d_in[11];
    const float* gW1 = (const float*)d_in[12];
    const float* gB1 = (const float*)d_in[13];
    const float* gW2 = (const float*)d_in[14];
    const float* gB2 = (const float*)d_in[15];
    float* out = (float*)d_out;

    char* ws = (char*)d_ws;
    float*  xb0    = (float*)(ws);                 // 3,200,000
    int*    off    = (int*)  (ws + 3200000);       // 400,004 (aliases cnt)
    int*    cnt    = off;
    int*    bsum   = (int*)  (ws + 3600064);       // 392
    float*  esum   = (float*)(ws + 3601024);       // 2
    float*  nsum   = (float*)(ws + 3601056);       // 8
    float*  g1     = (float*)(ws + 3601088);
    float*  g2     = g1 + 1;
    float*  eb0    = (float*)(ws + 3601152);       // 12,800,000
    float4* rec    = (float4*)(ws + 16401152);     // 25,600,000
    float*  Pr     = (float*)(ws + 42001152);      // 6,400,000 (aliases posArr)
    int*    posArr = (int*)  Pr;
    float*  Pc     = (float*)(ws + 48401152);      // 6,400,000 -> ends 54,801,152
    float*  xb1    = out;                          // d_out doubles as x buffer

    dim3 blk(256);
    dim3 egrid(NE / 256);                          // 6250 (build/fill)
    dim3 e8grid((NO8 + 255) / 256);                // 782 (edge MLP, 8 edges/thread)
    dim3 ngrid((NN + 255) / 256);                  // 391

    // ---- build row-sorted packed records (once per call) ----
    hipMemsetAsync(cnt, 0, 400000, stream);
    hipMemsetAsync(esum, 0, 64, stream);
    build1_kernel<<<egrid, blk, 0, stream>>>(ei, cnt, posArr);
    scan1_kernel<<<NBLK_SCAN, SCAN_B, 0, stream>>>(cnt, bsum);
    scan3_kernel<<<NBLK_SCAN, SCAN_B, 0, stream>>>(cnt, bsum, off);
    fill2_kernel<<<egrid, blk, 0, stream>>>(ei, posArr, off, eattr, rec);
    prep_kernel<<<ngrid, blk, 0, stream>>>(x, eW1, Pr, Pc);   // posArr dead now

    // ---- layer 0: ein = rec.zw -> eout eb0; node fuses P for L1 ----
    edge_kernel<true, false, true><<<e8grid, blk, 0, stream>>>(rec, Pr, Pc,
        nullptr, g, eW1, eB1, eW2, eB2, eb0, esum);
    node_kernel<false, true, true><<<ngrid, blk, 0, stream>>>(x, eb0, rec, off, g,
        nW1, nB1, nW2, nB2, eW1 + 304, Pr, Pc, xb0, nsum);
    glob_kernel<<<1, 64, 0, stream>>>(esum, nsum, g, gW1, gB1, gW2, gB2, g1);

    // ---- layer 1: ein = eb0 -> eout rec.zw (full 16B rewrite); node reads rec
    hipMemsetAsync(esum, 0, 64, stream);
    edge_kernel<false, true, true><<<e8grid, blk, 0, stream>>>(rec, Pr, Pc,
        eb0, g1, eW1 + 304, eB1 + 16, eW2 + 32, eB2 + 2, nullptr, esum);
    node_kernel<true, true, true><<<ngrid, blk, 0, stream>>>(xb0, nullptr, rec, off, g1,
        nW1 + 176, nB1 + 16, nW2 + 128, nB2 + 8, eW1 + 608, Pr, Pc, xb1, nsum);
    glob_kernel<<<1, 64, 0, stream>>>(esum, nsum, g1, gW1 + 176, gB1 + 16, gW2 + 16, gB2 + 1, g2);

    // ---- layer 2: ein = rec.zw -> eout eb0; node output -> d_out ----
    edge_kernel<true, false, false><<<e8grid, blk, 0, stream>>>(rec, Pr, Pc,
        nullptr, g2, eW1 + 608, eB1 + 32, eW2 + 64, eB2 + 4, eb0, esum);
    node_kernel<false, false, false><<<ngrid, blk, 0, stream>>>(xb1, eb0, rec, off, g2,
        nW1 + 352, nB1 + 32, nW2 + 256, nB2 + 16, nullptr, nullptr, nullptr, out, nsum);
}